// Round 8
// baseline (347.525 us; speedup 1.0000x reference)
//
#include <hip/hip_runtime.h>
#include <hip/hip_bf16.h>
#include <stdint.h>
#include <type_traits>

#define DEVINL __device__ __forceinline__

typedef unsigned short u16;
typedef unsigned int   u32;
typedef short bf16x8 __attribute__((ext_vector_type(8)));
typedef float f32x4  __attribute__((ext_vector_type(4)));
typedef float f32x16 __attribute__((ext_vector_type(16)));

// ---- problem constants ----
constexpr int BB   = 2,  SS  = 2048, HID = 2048, NH = 16;
constexpr int NOPE = 128, VD = 128, QHD = 192;
constexpr int QL   = 1536, KVL = 512;
constexpr int TOK  = BB * SS;            // 4096 tokens
constexpr int NCOMB = 2176;              // ac row stride
constexpr int NREAL = 2112;              // real combined output cols (1536+512+64)
constexpr float SCALE2    = 0.10412907368573824f;   // 192^-0.5 * log2(e)
constexpr float THR_RAW   = 105.0f;                 // ~11 / SCALE2 (defer-max, raw units)
constexpr float LN1E4_32  = 0.28782313662425575f;   // ln(10000)/32

DEVINL float bf2f(u16 u) { union { u32 u; float f; } v; v.u = (u32)u << 16; return v.f; }
DEVINL u16 f2bf(float f) {
  union { float f; u32 u; } v; v.f = f;
  u32 r = v.u + 0x7fffu + ((v.u >> 16) & 1u);
  return (u16)(r >> 16);
}
DEVINL u32 pack2(float a, float b) { return (u32)f2bf(a) | ((u32)f2bf(b) << 16); }
DEVINL u32 cvtpk(float lo, float hi) {
  u32 r;
  asm("v_cvt_pk_bf16_f32 %0, %1, %2" : "=v"(r) : "v"(lo), "v"(hi));
  return r;
}

DEVINL float fexp2(float x) {
#if __has_builtin(__builtin_amdgcn_exp2f)
  return __builtin_amdgcn_exp2f(x);
#else
  return __expf(x * 0.6931471805599453f);
#endif
}

DEVINL void gload_lds16(const u16* g, u16* l) {
  __builtin_amdgcn_global_load_lds(
      (const __attribute__((address_space(1))) void*)g,
      (__attribute__((address_space(3))) void*)l, 16, 0, 0);
}

// ---------------- merged fp32 -> bf16 conversion (6 segments, one launch) ----------------
__global__ __launch_bounds__(256)
void k_f2bf_all(const float* __restrict__ s0, const float* __restrict__ s1,
                const float* __restrict__ s2, const float* __restrict__ s3,
                const float* __restrict__ s4, const float* __restrict__ s5,
                u16* __restrict__ d0, u16* __restrict__ d1, u16* __restrict__ d2,
                u16* __restrict__ d3, u16* __restrict__ d4, u16* __restrict__ d5) {
  long g = ((long)blockIdx.x * 256 + threadIdx.x) * 4;
  const float* s; u16* d; long off;
  if (g < 8388608L)       { s = s0; d = d0; off = g; }
  else if (g < 11534336L) { s = s1; d = d1; off = g - 8388608L; }
  else if (g < 12713984L) { s = s2; d = d2; off = g - 11534336L; }
  else if (g < 17432576L) { s = s3; d = d3; off = g - 12713984L; }
  else if (g < 19529728L) { s = s4; d = d4; off = g - 17432576L; }
  else                    { s = s5; d = d5; off = g - 19529728L; }
  float4 v = *(const float4*)(s + off);
  uint2 o; o.x = pack2(v.x, v.y); o.y = pack2(v.z, v.w);
  *(uint2*)(d + off) = o;
}

// ---------------- 256x256 8-phase NT GEMM body with pluggable epilogue ----------------
template <class EPI>
DEVINL void gemm256_body(const u16* __restrict__ A, const u16* __restrict__ Bw,
                         int K, int m0, int n0, u16* SA, u16* SB, EPI epi) {
  const int t = threadIdx.x;
  const int lane = t & 63, wave = t >> 6;
  const int wr = wave >> 2, wc = wave & 3;
  const int lq = lane & 15, lg = lane >> 4;
  const int NT = K >> 6;

  const int r0 = t >> 3;
  const int cs = ((t & 7) ^ (r0 & 7)) * 8;

  auto stageA = [&](int d, int h, int kt) {
    const u16* g = A + (size_t)(m0 + h * 128) * K + kt * 64;
    u16* l = SA + (d * 2 + h) * 8192;
    gload_lds16(g + (size_t)r0 * K + cs, l + t * 8);
    gload_lds16(g + (size_t)(r0 + 64) * K + cs, l + (t + 512) * 8);
  };
  auto stageB = [&](int d, int h, int kt) {
    const u16* g = Bw + (size_t)(n0 + h * 128) * K + kt * 64;
    u16* l = SB + (d * 2 + h) * 8192;
    gload_lds16(g + (size_t)r0 * K + cs, l + t * 8);
    gload_lds16(g + (size_t)(r0 + 64) * K + cs, l + (t + 512) * 8);
  };
  auto rdA = [&](int d, int m, int k) -> bf16x8 {
    int row = m * 16 + lq;
    return *(const bf16x8*)(SA + (d * 2 + wr) * 8192 + row * 64 + (((k * 4 + lg) ^ (row & 7)) * 8));
  };
  auto rdB = [&](int d, int n, int k) -> bf16x8 {
    int row = (wc & 1) * 64 + n * 16 + lq;
    return *(const bf16x8*)(SB + (d * 2 + (wc >> 1)) * 8192 + row * 64 + (((k * 4 + lg) ^ (row & 7)) * 8));
  };

  f32x4 acc[8][4] = {};
  bf16x8 a[8][2], b[4][2];

  stageA(0, 0, 0); stageA(0, 1, 0); stageB(0, 0, 0); stageB(0, 1, 0);
  if (NT > 1) { stageA(1, 0, 1); stageA(1, 1, 1); stageB(1, 0, 1); }
  asm volatile("s_waitcnt vmcnt(6)" ::: "memory");
  __builtin_amdgcn_s_barrier();

  for (int T = 0; T < NT; ++T) {
    const int d = T & 1;
#pragma unroll
    for (int m = 0; m < 4; ++m) { a[m][0] = rdA(d, m, 0); a[m][1] = rdA(d, m, 1); }
#pragma unroll
    for (int n = 0; n < 2; ++n) { b[n][0] = rdB(d, n, 0); b[n][1] = rdB(d, n, 1); }
    if (T + 1 < NT) stageB(d ^ 1, 1, T + 1);
    asm volatile("s_waitcnt lgkmcnt(8)" ::: "memory");
    __builtin_amdgcn_s_barrier();
    asm volatile("s_waitcnt lgkmcnt(0)" ::: "memory");
    __builtin_amdgcn_s_setprio(1);
#pragma unroll
    for (int m = 0; m < 4; ++m)
#pragma unroll
      for (int n = 0; n < 2; ++n) {
        acc[m][n] = __builtin_amdgcn_mfma_f32_16x16x32_bf16(a[m][0], b[n][0], acc[m][n], 0, 0, 0);
        acc[m][n] = __builtin_amdgcn_mfma_f32_16x16x32_bf16(a[m][1], b[n][1], acc[m][n], 0, 0, 0);
      }
    __builtin_amdgcn_s_setprio(0);
    __builtin_amdgcn_s_barrier();
#pragma unroll
    for (int m = 4; m < 8; ++m) { a[m][0] = rdA(d, m, 0); a[m][1] = rdA(d, m, 1); }
#pragma unroll
    for (int n = 2; n < 4; ++n) { b[n][0] = rdB(d, n, 0); b[n][1] = rdB(d, n, 1); }
    asm volatile("s_waitcnt lgkmcnt(8)" ::: "memory");
    __builtin_amdgcn_s_barrier();
    asm volatile("s_waitcnt lgkmcnt(0)" ::: "memory");
    __builtin_amdgcn_s_setprio(1);
#pragma unroll
    for (int m = 4; m < 8; ++m)
#pragma unroll
      for (int n = 0; n < 2; ++n) {
        acc[m][n] = __builtin_amdgcn_mfma_f32_16x16x32_bf16(a[m][0], b[n][0], acc[m][n], 0, 0, 0);
        acc[m][n] = __builtin_amdgcn_mfma_f32_16x16x32_bf16(a[m][1], b[n][1], acc[m][n], 0, 0, 0);
      }
    __builtin_amdgcn_s_setprio(0);
    __builtin_amdgcn_s_barrier();
    if (T + 2 < NT) { stageA(d, 0, T + 2); stageA(d, 1, T + 2); }
    __builtin_amdgcn_s_barrier();
    __builtin_amdgcn_s_setprio(1);
#pragma unroll
    for (int m = 0; m < 4; ++m)
#pragma unroll
      for (int n = 2; n < 4; ++n) {
        acc[m][n] = __builtin_amdgcn_mfma_f32_16x16x32_bf16(a[m][0], b[n][0], acc[m][n], 0, 0, 0);
        acc[m][n] = __builtin_amdgcn_mfma_f32_16x16x32_bf16(a[m][1], b[n][1], acc[m][n], 0, 0, 0);
      }
    __builtin_amdgcn_s_setprio(0);
    __builtin_amdgcn_s_barrier();
    if (T + 2 < NT) stageB(d, 0, T + 2);
    __builtin_amdgcn_s_barrier();
    __builtin_amdgcn_s_setprio(1);
#pragma unroll
    for (int m = 4; m < 8; ++m)
#pragma unroll
      for (int n = 2; n < 4; ++n) {
        acc[m][n] = __builtin_amdgcn_mfma_f32_16x16x32_bf16(a[m][0], b[n][0], acc[m][n], 0, 0, 0);
        acc[m][n] = __builtin_amdgcn_mfma_f32_16x16x32_bf16(a[m][1], b[n][1], acc[m][n], 0, 0, 0);
      }
    __builtin_amdgcn_s_setprio(0);
    if (T + 2 < NT)      asm volatile("s_waitcnt vmcnt(6)" ::: "memory");
    else if (T + 1 < NT) asm volatile("s_waitcnt vmcnt(0)" ::: "memory");
    __builtin_amdgcn_s_barrier();
  }

#pragma unroll
  for (int m = 0; m < 8; ++m)
#pragma unroll
    for (int n = 0; n < 4; ++n)
      epi(m0 + wr * 128 + m * 16 + lg * 4, n0 + wc * 64 + n * 16 + lq, acc[m][n]);
}

// GEMM1: hidden @ w_comb^T -> ac (guarded cols)
__global__ __launch_bounds__(512, 2)
void k_gemm1(const u16* __restrict__ A, const u16* __restrict__ Bw, u16* __restrict__ C) {
  __shared__ u16 SA[2 * 2 * 8192];
  __shared__ u16 SB[2 * 2 * 8192];
  auto epi = [&](int row, int col, const f32x4& v) {
    if (col < NREAL) {
#pragma unroll
      for (int r = 0; r < 4; ++r) C[(size_t)(row + r) * NCOMB + col] = f2bf(v[r]);
    }
  };
  gemm256_body(A, Bw, HID, blockIdx.y * 256, blockIdx.x * 256, SA, SB, epi);
}

// grouped qb (192 blocks) + kvb (256 blocks, epilogue splits KN / VT-transposed)
__global__ __launch_bounds__(512, 2)
void k_gemm_qbkvb(const u16* __restrict__ qa_n, const u16* __restrict__ w_qb,
                  u16* __restrict__ qfull, const u16* __restrict__ kv_n,
                  const u16* __restrict__ w_kvb, u16* __restrict__ KN,
                  u16* __restrict__ VT) {
  __shared__ u16 SA[2 * 2 * 8192];
  __shared__ u16 SB[2 * 2 * 8192];
  const int bx = blockIdx.x;
  if (bx < 192) {
    auto epi = [&](int row, int col, const f32x4& v) {
#pragma unroll
      for (int r = 0; r < 4; ++r) qfull[(size_t)(row + r) * 3072 + col] = f2bf(v[r]);
    };
    gemm256_body(qa_n, w_qb, QL, (bx / 12) * 256, (bx % 12) * 256, SA, SB, epi);
  } else {
    const int i = bx - 192;
    auto epi = [&](int row, int col, const f32x4& v) {
      const int h = col >> 8, d = col & 255;
      if (d < 128) {
#pragma unroll
        for (int r = 0; r < 4; ++r) KN[(size_t)(row + r) * 2048 + h * 128 + d] = f2bf(v[r]);
      } else {
        uint2 o; o.x = pack2(v[0], v[1]); o.y = pack2(v[2], v[3]);
        *(uint2*)(VT + ((size_t)((row >> 11) * 16 + h) * 128 + (d - 128)) * SS + (row & (SS - 1))) = o;
      }
    };
    gemm256_body(kv_n, w_kvb, KVL, (i / 16) * 256, (i % 16) * 256, SA, SB, epi);
  }
}

// o_proj -> fp32 d_out
__global__ __launch_bounds__(512, 2)
void k_oproj(const u16* __restrict__ A, const u16* __restrict__ Bw, float* __restrict__ C) {
  __shared__ u16 SA[2 * 2 * 8192];
  __shared__ u16 SB[2 * 2 * 8192];
  auto epi = [&](int row, int col, const f32x4& v) {
#pragma unroll
    for (int r = 0; r < 4; ++r) C[(size_t)(row + r) * HID + col] = v[r];
  };
  gemm256_body(A, Bw, NH * VD, blockIdx.y * 256, blockIdx.x * 256, SA, SB, epi);
}

// ---------------- fused per-token: RMSNorm(q), RMSNorm(kv), rope(k_pe) ----------------
__global__ __launch_bounds__(256)
void k_token(const u16* __restrict__ ac, const float* __restrict__ qw,
             const float* __restrict__ kvw, const int* __restrict__ pos,
             u16* __restrict__ qa_n, u16* __restrict__ kv_n, u16* __restrict__ peR) {
  const int row = blockIdx.x, t = threadIdx.x;
  const u16* xr = ac + (size_t)row * NCOMB;
  float sq = 0.f, skv = 0.f;
  if (t < 192) {
    bf16x8 v = *(const bf16x8*)(xr + t * 8);
#pragma unroll
    for (int j = 0; j < 8; ++j) { float f = bf2f((u16)v[j]); sq += f * f; }
  }
  if (t < 64) {
    bf16x8 v = *(const bf16x8*)(xr + QL + t * 8);
#pragma unroll
    for (int j = 0; j < 8; ++j) { float f = bf2f((u16)v[j]); skv += f * f; }
  }
#pragma unroll
  for (int o = 1; o < 64; o <<= 1) { sq += __shfl_xor(sq, o); skv += __shfl_xor(skv, o); }
  __shared__ float red[4][2];
  if ((t & 63) == 0) { red[t >> 6][0] = sq; red[t >> 6][1] = skv; }
  __syncthreads();
  const float rsq  = rsqrtf((red[0][0] + red[1][0] + red[2][0] + red[3][0]) / (float)QL  + 1e-6f);
  const float rskv = rsqrtf((red[0][1] + red[1][1] + red[2][1] + red[3][1]) / (float)KVL + 1e-6f);
  if (t < 192) {
    bf16x8 v = *(const bf16x8*)(xr + t * 8);
    u32 o4[4];
#pragma unroll
    for (int j = 0; j < 4; ++j)
      o4[j] = pack2(bf2f((u16)v[2 * j]) * rsq * qw[t * 8 + 2 * j],
                    bf2f((u16)v[2 * j + 1]) * rsq * qw[t * 8 + 2 * j + 1]);
    *(uint4*)(qa_n + (size_t)row * QL + t * 8) = *(uint4*)o4;
  }
  if (t < 64) {
    bf16x8 v = *(const bf16x8*)(xr + QL + t * 8);
    u32 o4[4];
#pragma unroll
    for (int j = 0; j < 4; ++j)
      o4[j] = pack2(bf2f((u16)v[2 * j]) * rskv * kvw[t * 8 + 2 * j],
                    bf2f((u16)v[2 * j + 1]) * rskv * kvw[t * 8 + 2 * j + 1]);
    *(uint4*)(kv_n + (size_t)row * KVL + t * 8) = *(uint4*)o4;
  }
  if (t < 32) {
    const u16* src = xr + (QL + KVL) + 2 * t;
    float x0 = bf2f(src[0]), x1 = bf2f(src[1]);
    float ang = (float)pos[row] * __expf(-(float)t * LN1E4_32);
    float sn, cs; sincosf(ang, &sn, &cs);
    *(u32*)(peR + (size_t)row * 64 + 2 * t) = pack2(x0 * cs - x1 * sn, x1 * cs + x0 * sn);
  }
}

// ---------------- causal flash attention: 32x32 MFMA, in-register P (T12) ----------------
// 512 blocks x 4 waves; wave owns 32 q-rows (QBLK=32), KVBLK=32.
// S^T = mfma_32x32x16(K, Q): col=q=lane&31, row=(reg&3)+8*(reg>>2)+4*(lane>>5).
// P -> PV B-frags via 8 cvt_pk + 4 permlane32_swap (no LDS P buffer).
// id layout: ids x and x+256 (same CU under XCD round-robin) have complementary c -> uniform work.
__global__ __launch_bounds__(256)
void k_attn(const u16* __restrict__ Qf, const u16* __restrict__ KN,
            const u16* __restrict__ peR, const u16* __restrict__ VT,
            const int* __restrict__ pos, u16* __restrict__ Oa) {
  const int id = blockIdx.x;
  const int idh = id & 255;
  const int c = (id < 256) ? (15 - (idh >> 5)) : (idh >> 5);
  const int bh = idh & 31;
  const int b = bh >> 4, h = bh & 15;
  const int t = threadIdx.x, lane = t & 63, wave = t >> 6;
  const int lc = lane & 31, hi = lane >> 5;
  const int q0 = c * 128 + wave * 32;
  const size_t vb = (size_t)bh * VD * SS;

  __shared__ u16 Ks[2][32 * 192];     // row=key, 24 slots of 16B, slot^=(row&7)
  __shared__ u16 Vs[2][128 * 32];     // row=v-dim, 4 slots of 16B, slot^=((row>>1)&3)

  auto stage = [&](int buf, int kb) {
#pragma unroll
    for (int i = 0; i < 3; ++i) {      // K: 768 16B chunks (nope from KN, pe from peR)
      int cc = t + 256 * i, row = cc / 24, sl = cc % 24;
      int sg = sl ^ (row & 7);
      const u16* src = (sg < 16)
          ? KN + (size_t)(b * SS + kb + row) * 2048 + h * 128 + sg * 8
          : peR + (size_t)(b * SS + kb + row) * 64 + (sg - 16) * 8;
      gload_lds16(src, &Ks[buf][0] + cc * 8);
    }
#pragma unroll
    for (int i = 0; i < 2; ++i) {      // V: 512 16B chunks
      int cc = t + 256 * i, row = cc >> 2, sl = cc & 3;
      gload_lds16(VT + vb + (size_t)row * SS + kb + (sl ^ ((row >> 1) & 3)) * 8,
                  &Vs[buf][0] + cc * 8);
    }
  };

  const int qrow = q0 + lc;
  const int token = b * SS + qrow;
  // Q fragments: 12 chunks of 16 dims; chunk ch: d = ch*16 + hi*8 + [0..8)
  bf16x8 qf[12];
#pragma unroll
  for (int ch = 0; ch < 12; ++ch)
    qf[ch] = *(const bf16x8*)(Qf + (size_t)token * (NH * QHD) + h * QHD + ch * 16 + hi * 8);
  // in-reg RoPE on q_pe chunks 8..11 (pairs are within-chunk, start even)
  const float posv = (float)pos[token];
#pragma unroll
  for (int ch = 8; ch < 12; ++ch)
#pragma unroll
    for (int p = 0; p < 4; ++p) {
      const int jj = (ch - 8) * 8 + hi * 4 + p;
      const float ang = posv * __expf(-(float)jj * LN1E4_32);
      float sn, cs; sincosf(ang, &sn, &cs);
      const float x0 = bf2f((u16)qf[ch][2 * p]), x1 = bf2f((u16)qf[ch][2 * p + 1]);
      qf[ch][2 * p]     = (short)f2bf(x0 * cs - x1 * sn);
      qf[ch][2 * p + 1] = (short)f2bf(x1 * cs + x0 * sn);
    }

  float m = -1e30f, lsum = 0.f;        // m in RAW score units
  f32x16 o0 = {}, o1 = {}, o2 = {}, o3 = {};   // O^T v-blocks 0..3 (128 v dims)

  const int nt = 4 * (c + 1);

  stage(0, 0);
  asm volatile("s_waitcnt vmcnt(0)" ::: "memory");
  __builtin_amdgcn_s_barrier();

  for (int tt = 0; tt < nt; ++tt) {
    const int cur = tt & 1;
    if (tt + 1 < nt) stage(cur ^ 1, (tt + 1) * 32);
    const int kb = tt * 32;

    if (kb <= q0) {                    // wave-uniform skip of fully-masked tiles
      f32x16 s = {};
      __builtin_amdgcn_s_setprio(1);
#pragma unroll
      for (int ch = 0; ch < 12; ++ch) {
        const int ps = (2 * ch + hi) ^ (lc & 7);
        bf16x8 kf = *(const bf16x8*)(&Ks[cur][0] + (lc * 24 + ps) * 8);
        s = __builtin_amdgcn_mfma_f32_32x32x16_bf16(kf, qf[ch], s, 0, 0, 0);
      }
      __builtin_amdgcn_s_setprio(0);

      if (kb == q0) {                  // diagonal tile: mask key-row > q-col
#pragma unroll
        for (int r = 0; r < 16; ++r) {
          const int krow = (r & 3) + 8 * (r >> 2) + 4 * hi;
          s[r] = (krow <= lc) ? s[r] : -3e38f;
        }
      }
      float mx = s[0];
#pragma unroll
      for (int r = 1; r < 16; ++r) mx = fmaxf(mx, s[r]);
      mx = fmaxf(mx, __shfl_xor(mx, 32));
      if (!__all(mx - m <= THR_RAW)) {
        float mnew = fmaxf(m, mx);
        float fac = fexp2((m - mnew) * SCALE2);
        lsum *= fac;
#pragma unroll
        for (int r = 0; r < 16; ++r) { o0[r] *= fac; o1[r] *= fac; o2[r] *= fac; o3[r] *= fac; }
        m = mnew;
      }
      const float ms = m * SCALE2;
      float p[16];
#pragma unroll
      for (int r = 0; r < 16; ++r) p[r] = fexp2(fmaf(s[r], SCALE2, -ms));
      float ps2 = 0.f;
#pragma unroll
      for (int r = 0; r < 16; ++r) ps2 += p[r];
      ps2 += __shfl_xor(ps2, 32);
      lsum += ps2;

      // pack P^T B-frags: kk0 = keys 0..15, kk1 = keys 16..31
      u32 w0 = cvtpk(p[0], p[1]),  w1 = cvtpk(p[2], p[3]);
      u32 w2 = cvtpk(p[4], p[5]),  w3 = cvtpk(p[6], p[7]);
      u32 w4 = cvtpk(p[8], p[9]),  w5 = cvtpk(p[10], p[11]);
      u32 w6 = cvtpk(p[12], p[13]), w7 = cvtpk(p[14], p[15]);
      asm volatile("v_permlane32_swap_b32 %0, %1" : "+v"(w0), "+v"(w2));
      asm volatile("v_permlane32_swap_b32 %0, %1" : "+v"(w1), "+v"(w3));
      asm volatile("v_permlane32_swap_b32 %0, %1" : "+v"(w4), "+v"(w6));
      asm volatile("v_permlane32_swap_b32 %0, %1" : "+v"(w5), "+v"(w7));
      u32 pk0[4] = {w0, w1, w2, w3};
      u32 pk1[4] = {w4, w5, w6, w7};
      bf16x8 pf0, pf1;
      __builtin_memcpy(&pf0, pk0, 16);
      __builtin_memcpy(&pf1, pk1, 16);

      __builtin_amdgcn_s_setprio(1);
#pragma unroll
      for (int vblk = 0; vblk < 4; ++vblk) {
        const int rv = vblk * 32 + lc;
        const int sw = (rv >> 1) & 3;
        bf16x8 vf0 = *(const bf16x8*)(&Vs[cur][0] + rv * 32 + ((hi ^ sw) * 8));
        bf16x8 vf1 = *(const bf16x8*)(&Vs[cur][0] + rv * 32 + (((2 + hi) ^ sw) * 8));
        f32x16& oo = vblk == 0 ? o0 : vblk == 1 ? o1 : vblk == 2 ? o2 : o3;
        oo = __builtin_amdgcn_mfma_f32_32x32x16_bf16(vf0, pf0, oo, 0, 0, 0);
        oo = __builtin_amdgcn_mfma_f32_32x32x16_bf16(vf1, pf1, oo, 0, 0, 0);
      }
      __builtin_amdgcn_s_setprio(0);
    }

    asm volatile("s_waitcnt vmcnt(0)" ::: "memory");
    __builtin_amdgcn_s_barrier();
  }

  const float inv = 1.0f / lsum;
  u16* orow = Oa + (size_t)token * (NH * VD) + h * VD;
#pragma unroll
  for (int vblk = 0; vblk < 4; ++vblk) {
    const f32x16& oo = vblk == 0 ? o0 : vblk == 1 ? o1 : vblk == 2 ? o2 : o3;
#pragma unroll
    for (int grp = 0; grp < 4; ++grp) {
      uint2 w;
      w.x = cvtpk(oo[grp * 4 + 0] * inv, oo[grp * 4 + 1] * inv);
      w.y = cvtpk(oo[grp * 4 + 2] * inv, oo[grp * 4 + 3] * inv);
      *(uint2*)(orow + vblk * 32 + grp * 8 + hi * 4) = w;
    }
  }
}

// ---------------- host launch ----------------
extern "C" void kernel_launch(void* const* d_in, const int* in_sizes, int n_in,
                              void* d_out, int out_size, void* d_ws, size_t ws_size,
                              hipStream_t stream) {
  (void)in_sizes; (void)n_in; (void)out_size; (void)ws_size;
  const float* hidden  = (const float*)d_in[0];
  const int*   pos     = (const int*)d_in[2];
  const float* q_a_w   = (const float*)d_in[3];
  const float* q_a_ln  = (const float*)d_in[4];
  const float* q_b_w   = (const float*)d_in[5];
  const float* kv_a_w  = (const float*)d_in[6];
  const float* kv_a_ln = (const float*)d_in[7];
  const float* kv_b_w  = (const float*)d_in[8];
  const float* o_w     = (const float*)d_in[9];

  char* ws = (char*)d_ws;
  u16* hid_bf = (u16*)(ws + 0);          // dead after GEMM1; region reused as VT
  u16* VT     = (u16*)(ws + 0);
  u16* w_comb = (u16*)(ws + 16777216);
  u16* w_qb   = (u16*)(ws + 25690112);
  u16* w_kvb  = (u16*)(ws + 35127296);
  u16* w_o    = (u16*)(ws + 39321600);
  u16* ac     = (u16*)(ws + 47710208);   // dead after k_token; reused as attn_o
  u16* attn_o = (u16*)(ws + 47710208);
  u16* qa_n   = (u16*)(ws + 65536000);
  u16* kv_n   = (u16*)(ws + 78118912);
  u16* qfull  = (u16*)(ws + 82313216);
  u16* KN     = (u16*)(ws + 107479040);  // TOK x 2048 compact k_nope
  u16* peR    = (u16*)(ws + 141033472);  // TOK x 64 roped k_pe

  k_f2bf_all<<<23168, 256, 0, stream>>>(hidden, q_a_w, kv_a_w, q_b_w, kv_b_w, o_w,
                                        hid_bf, w_comb, w_comb + QL * HID, w_qb, w_kvb, w_o);
  k_gemm1<<<dim3(9, TOK / 256), 512, 0, stream>>>(hid_bf, w_comb, ac);
  k_token<<<TOK, 256, 0, stream>>>(ac, q_a_ln, kv_a_ln, pos, qa_n, kv_n, peR);
  k_gemm_qbkvb<<<448, 512, 0, stream>>>(qa_n, w_qb, qfull, kv_n, w_kvb, KN, VT);
  k_attn<<<512, 256, 0, stream>>>(qfull, KN, peR, VT, pos, attn_o);
  k_oproj<<<dim3(8, TOK / 256), 512, 0, stream>>>(attn_o, w_o, (float*)d_out);
}

// Round 9
// 312.830 us; speedup vs baseline: 1.1109x; 1.1109x over previous
//
#include <hip/hip_runtime.h>
#include <hip/hip_bf16.h>
#include <stdint.h>
#include <type_traits>

#define DEVINL __device__ __forceinline__

typedef unsigned short u16;
typedef unsigned int   u32;
typedef short bf16x8 __attribute__((ext_vector_type(8)));
typedef float f32x4  __attribute__((ext_vector_type(4)));

// ---- problem constants ----
constexpr int BB   = 2,  SS  = 2048, HID = 2048, NH = 16;
constexpr int NOPE = 128, VD = 128, QHD = 192;
constexpr int QL   = 1536, KVL = 512;
constexpr int TOK  = BB * SS;            // 4096 tokens
constexpr int NCOMB = 2176;              // ac row stride
constexpr int NREAL = 2112;              // real combined output cols (1536+512+64)
constexpr float SCALE2    = 0.10412907368573824f;   // 192^-0.5 * log2(e)
constexpr float THR_RAW   = 105.0f;                 // ~11 / SCALE2 (defer-max, raw units)
constexpr float LN1E4_32  = 0.28782313662425575f;   // ln(10000)/32

DEVINL float bf2f(u16 u) { union { u32 u; float f; } v; v.u = (u32)u << 16; return v.f; }
DEVINL u16 f2bf(float f) {
  union { float f; u32 u; } v; v.f = f;
  u32 r = v.u + 0x7fffu + ((v.u >> 16) & 1u);
  return (u16)(r >> 16);
}
DEVINL u32 pack2(float a, float b) { return (u32)f2bf(a) | ((u32)f2bf(b) << 16); }
DEVINL u32 cvtpk(float lo, float hi) {
  u32 r;
  asm("v_cvt_pk_bf16_f32 %0, %1, %2" : "=v"(r) : "v"(lo), "v"(hi));
  return r;
}

DEVINL float fexp2(float x) {
#if __has_builtin(__builtin_amdgcn_exp2f)
  return __builtin_amdgcn_exp2f(x);
#else
  return __expf(x * 0.6931471805599453f);
#endif
}

DEVINL void gload_lds16(const u16* g, u16* l) {
  __builtin_amdgcn_global_load_lds(
      (const __attribute__((address_space(1))) void*)g,
      (__attribute__((address_space(3))) void*)l, 16, 0, 0);
}

// ---------------- merged fp32 -> bf16 conversion (6 segments, one launch) ----------------
__global__ __launch_bounds__(256)
void k_f2bf_all(const float* __restrict__ s0, const float* __restrict__ s1,
                const float* __restrict__ s2, const float* __restrict__ s3,
                const float* __restrict__ s4, const float* __restrict__ s5,
                u16* __restrict__ d0, u16* __restrict__ d1, u16* __restrict__ d2,
                u16* __restrict__ d3, u16* __restrict__ d4, u16* __restrict__ d5) {
  long g = ((long)blockIdx.x * 256 + threadIdx.x) * 4;
  const float* s; u16* d; long off;
  if (g < 8388608L)       { s = s0; d = d0; off = g; }
  else if (g < 11534336L) { s = s1; d = d1; off = g - 8388608L; }
  else if (g < 12713984L) { s = s2; d = d2; off = g - 11534336L; }
  else if (g < 17432576L) { s = s3; d = d3; off = g - 12713984L; }
  else if (g < 19529728L) { s = s4; d = d4; off = g - 17432576L; }
  else                    { s = s5; d = d5; off = g - 19529728L; }
  float4 v = *(const float4*)(s + off);
  uint2 o; o.x = pack2(v.x, v.y); o.y = pack2(v.z, v.w);
  *(uint2*)(d + off) = o;
}

// ---------------- 256x256 8-phase NT GEMM body with pluggable epilogue ----------------
template <class EPI>
DEVINL void gemm256_body(const u16* __restrict__ A, const u16* __restrict__ Bw,
                         int K, int m0, int n0, u16* SA, u16* SB, EPI epi) {
  const int t = threadIdx.x;
  const int lane = t & 63, wave = t >> 6;
  const int wr = wave >> 2, wc = wave & 3;
  const int lq = lane & 15, lg = lane >> 4;
  const int NT = K >> 6;

  const int r0 = t >> 3;
  const int cs = ((t & 7) ^ (r0 & 7)) * 8;

  auto stageA = [&](int d, int h, int kt) {
    const u16* g = A + (size_t)(m0 + h * 128) * K + kt * 64;
    u16* l = SA + (d * 2 + h) * 8192;
    gload_lds16(g + (size_t)r0 * K + cs, l + t * 8);
    gload_lds16(g + (size_t)(r0 + 64) * K + cs, l + (t + 512) * 8);
  };
  auto stageB = [&](int d, int h, int kt) {
    const u16* g = Bw + (size_t)(n0 + h * 128) * K + kt * 64;
    u16* l = SB + (d * 2 + h) * 8192;
    gload_lds16(g + (size_t)r0 * K + cs, l + t * 8);
    gload_lds16(g + (size_t)(r0 + 64) * K + cs, l + (t + 512) * 8);
  };
  auto rdA = [&](int d, int m, int k) -> bf16x8 {
    int row = m * 16 + lq;
    return *(const bf16x8*)(SA + (d * 2 + wr) * 8192 + row * 64 + (((k * 4 + lg) ^ (row & 7)) * 8));
  };
  auto rdB = [&](int d, int n, int k) -> bf16x8 {
    int row = (wc & 1) * 64 + n * 16 + lq;
    return *(const bf16x8*)(SB + (d * 2 + (wc >> 1)) * 8192 + row * 64 + (((k * 4 + lg) ^ (row & 7)) * 8));
  };

  f32x4 acc[8][4] = {};
  bf16x8 a[8][2], b[4][2];

  stageA(0, 0, 0); stageA(0, 1, 0); stageB(0, 0, 0); stageB(0, 1, 0);
  if (NT > 1) { stageA(1, 0, 1); stageA(1, 1, 1); stageB(1, 0, 1); }
  asm volatile("s_waitcnt vmcnt(6)" ::: "memory");
  __builtin_amdgcn_s_barrier();

  for (int T = 0; T < NT; ++T) {
    const int d = T & 1;
#pragma unroll
    for (int m = 0; m < 4; ++m) { a[m][0] = rdA(d, m, 0); a[m][1] = rdA(d, m, 1); }
#pragma unroll
    for (int n = 0; n < 2; ++n) { b[n][0] = rdB(d, n, 0); b[n][1] = rdB(d, n, 1); }
    if (T + 1 < NT) stageB(d ^ 1, 1, T + 1);
    asm volatile("s_waitcnt lgkmcnt(8)" ::: "memory");
    __builtin_amdgcn_s_barrier();
    asm volatile("s_waitcnt lgkmcnt(0)" ::: "memory");
    __builtin_amdgcn_s_setprio(1);
#pragma unroll
    for (int m = 0; m < 4; ++m)
#pragma unroll
      for (int n = 0; n < 2; ++n) {
        acc[m][n] = __builtin_amdgcn_mfma_f32_16x16x32_bf16(a[m][0], b[n][0], acc[m][n], 0, 0, 0);
        acc[m][n] = __builtin_amdgcn_mfma_f32_16x16x32_bf16(a[m][1], b[n][1], acc[m][n], 0, 0, 0);
      }
    __builtin_amdgcn_s_setprio(0);
    __builtin_amdgcn_s_barrier();
#pragma unroll
    for (int m = 4; m < 8; ++m) { a[m][0] = rdA(d, m, 0); a[m][1] = rdA(d, m, 1); }
#pragma unroll
    for (int n = 2; n < 4; ++n) { b[n][0] = rdB(d, n, 0); b[n][1] = rdB(d, n, 1); }
    asm volatile("s_waitcnt lgkmcnt(8)" ::: "memory");
    __builtin_amdgcn_s_barrier();
    asm volatile("s_waitcnt lgkmcnt(0)" ::: "memory");
    __builtin_amdgcn_s_setprio(1);
#pragma unroll
    for (int m = 4; m < 8; ++m)
#pragma unroll
      for (int n = 0; n < 2; ++n) {
        acc[m][n] = __builtin_amdgcn_mfma_f32_16x16x32_bf16(a[m][0], b[n][0], acc[m][n], 0, 0, 0);
        acc[m][n] = __builtin_amdgcn_mfma_f32_16x16x32_bf16(a[m][1], b[n][1], acc[m][n], 0, 0, 0);
      }
    __builtin_amdgcn_s_setprio(0);
    __builtin_amdgcn_s_barrier();
    if (T + 2 < NT) { stageA(d, 0, T + 2); stageA(d, 1, T + 2); }
    __builtin_amdgcn_s_barrier();
    __builtin_amdgcn_s_setprio(1);
#pragma unroll
    for (int m = 0; m < 4; ++m)
#pragma unroll
      for (int n = 2; n < 4; ++n) {
        acc[m][n] = __builtin_amdgcn_mfma_f32_16x16x32_bf16(a[m][0], b[n][0], acc[m][n], 0, 0, 0);
        acc[m][n] = __builtin_amdgcn_mfma_f32_16x16x32_bf16(a[m][1], b[n][1], acc[m][n], 0, 0, 0);
      }
    __builtin_amdgcn_s_setprio(0);
    __builtin_amdgcn_s_barrier();
    if (T + 2 < NT) stageB(d, 0, T + 2);
    __builtin_amdgcn_s_barrier();
    __builtin_amdgcn_s_setprio(1);
#pragma unroll
    for (int m = 4; m < 8; ++m)
#pragma unroll
      for (int n = 2; n < 4; ++n) {
        acc[m][n] = __builtin_amdgcn_mfma_f32_16x16x32_bf16(a[m][0], b[n][0], acc[m][n], 0, 0, 0);
        acc[m][n] = __builtin_amdgcn_mfma_f32_16x16x32_bf16(a[m][1], b[n][1], acc[m][n], 0, 0, 0);
      }
    __builtin_amdgcn_s_setprio(0);
    if (T + 2 < NT)      asm volatile("s_waitcnt vmcnt(6)" ::: "memory");
    else if (T + 1 < NT) asm volatile("s_waitcnt vmcnt(0)" ::: "memory");
    __builtin_amdgcn_s_barrier();
  }

#pragma unroll
  for (int m = 0; m < 8; ++m)
#pragma unroll
    for (int n = 0; n < 4; ++n)
      epi(m0 + wr * 128 + m * 16 + lg * 4, n0 + wc * 64 + n * 16 + lq, acc[m][n]);
}

// GEMM1: hidden @ w_comb^T -> ac. Grid 144 (1D), XCD-grouped panels:
// xcd = id&7 owns B-panel xcd (slots 0..15 = M blocks); slots 16..17 cover panel 8.
__global__ __launch_bounds__(512, 2)
void k_gemm1(const u16* __restrict__ A, const u16* __restrict__ Bw, u16* __restrict__ C) {
  __shared__ u16 SA[2 * 2 * 8192];
  __shared__ u16 SB[2 * 2 * 8192];
  const int raw = blockIdx.x, xcd = raw & 7, slot = raw >> 3;
  int m0, n0;
  if (slot < 16) { n0 = xcd * 256; m0 = slot * 256; }
  else           { n0 = 2048;      m0 = (xcd * 2 + (slot - 16)) * 256; }
  auto epi = [&](int row, int col, const f32x4& v) {
    if (col < NREAL) {
#pragma unroll
      for (int r = 0; r < 4; ++r) C[(size_t)(row + r) * NCOMB + col] = f2bf(v[r]);
    }
  };
  gemm256_body(A, Bw, HID, m0, n0, SA, SB, epi);
}

// grouped qb (192 blocks) + kvb (256 blocks, epilogue splits KN / VT-transposed)
__global__ __launch_bounds__(512, 2)
void k_gemm_qbkvb(const u16* __restrict__ qa_n, const u16* __restrict__ w_qb,
                  u16* __restrict__ qfull, const u16* __restrict__ kv_n,
                  const u16* __restrict__ w_kvb, u16* __restrict__ KN,
                  u16* __restrict__ VT) {
  __shared__ u16 SA[2 * 2 * 8192];
  __shared__ u16 SB[2 * 2 * 8192];
  const int bx = blockIdx.x;
  if (bx < 192) {
    auto epi = [&](int row, int col, const f32x4& v) {
#pragma unroll
      for (int r = 0; r < 4; ++r) qfull[(size_t)(row + r) * 3072 + col] = f2bf(v[r]);
    };
    gemm256_body(qa_n, w_qb, QL, (bx / 12) * 256, (bx % 12) * 256, SA, SB, epi);
  } else {
    const int i = bx - 192;
    auto epi = [&](int row, int col, const f32x4& v) {
      const int h = col >> 8, d = col & 255;
      if (d < 128) {
#pragma unroll
        for (int r = 0; r < 4; ++r) KN[(size_t)(row + r) * 2048 + h * 128 + d] = f2bf(v[r]);
      } else {
        uint2 o; o.x = pack2(v[0], v[1]); o.y = pack2(v[2], v[3]);
        *(uint2*)(VT + ((size_t)((row >> 11) * 16 + h) * 128 + (d - 128)) * SS + (row & (SS - 1))) = o;
      }
    };
    gemm256_body(kv_n, w_kvb, KVL, (i / 16) * 256, (i % 16) * 256, SA, SB, epi);
  }
}

// o_proj -> fp32 d_out. Grid 128 (1D), XCD-grouped: xcd = id&7 owns B-panel xcd.
__global__ __launch_bounds__(512, 2)
void k_oproj(const u16* __restrict__ A, const u16* __restrict__ Bw, float* __restrict__ C) {
  __shared__ u16 SA[2 * 2 * 8192];
  __shared__ u16 SB[2 * 2 * 8192];
  const int raw = blockIdx.x;
  const int n0 = (raw & 7) * 256, m0 = (raw >> 3) * 256;
  auto epi = [&](int row, int col, const f32x4& v) {
#pragma unroll
    for (int r = 0; r < 4; ++r) C[(size_t)(row + r) * HID + col] = v[r];
  };
  gemm256_body(A, Bw, NH * VD, m0, n0, SA, SB, epi);
}

// ---------------- fused per-token: RMSNorm(q), RMSNorm(kv), rope(k_pe) ----------------
__global__ __launch_bounds__(256)
void k_token(const u16* __restrict__ ac, const float* __restrict__ qw,
             const float* __restrict__ kvw, const int* __restrict__ pos,
             u16* __restrict__ qa_n, u16* __restrict__ kv_n, u16* __restrict__ peR) {
  const int row = blockIdx.x, t = threadIdx.x;
  const u16* xr = ac + (size_t)row * NCOMB;
  float sq = 0.f, skv = 0.f;
  if (t < 192) {
    bf16x8 v = *(const bf16x8*)(xr + t * 8);
#pragma unroll
    for (int j = 0; j < 8; ++j) { float f = bf2f((u16)v[j]); sq += f * f; }
  }
  if (t < 64) {
    bf16x8 v = *(const bf16x8*)(xr + QL + t * 8);
#pragma unroll
    for (int j = 0; j < 8; ++j) { float f = bf2f((u16)v[j]); skv += f * f; }
  }
#pragma unroll
  for (int o = 1; o < 64; o <<= 1) { sq += __shfl_xor(sq, o); skv += __shfl_xor(skv, o); }
  __shared__ float red[4][2];
  if ((t & 63) == 0) { red[t >> 6][0] = sq; red[t >> 6][1] = skv; }
  __syncthreads();
  const float rsq  = rsqrtf((red[0][0] + red[1][0] + red[2][0] + red[3][0]) / (float)QL  + 1e-6f);
  const float rskv = rsqrtf((red[0][1] + red[1][1] + red[2][1] + red[3][1]) / (float)KVL + 1e-6f);
  if (t < 192) {
    bf16x8 v = *(const bf16x8*)(xr + t * 8);
    u32 o4[4];
#pragma unroll
    for (int j = 0; j < 4; ++j)
      o4[j] = pack2(bf2f((u16)v[2 * j]) * rsq * qw[t * 8 + 2 * j],
                    bf2f((u16)v[2 * j + 1]) * rsq * qw[t * 8 + 2 * j + 1]);
    *(uint4*)(qa_n + (size_t)row * QL + t * 8) = *(uint4*)o4;
  }
  if (t < 64) {
    bf16x8 v = *(const bf16x8*)(xr + QL + t * 8);
    u32 o4[4];
#pragma unroll
    for (int j = 0; j < 4; ++j)
      o4[j] = pack2(bf2f((u16)v[2 * j]) * rskv * kvw[t * 8 + 2 * j],
                    bf2f((u16)v[2 * j + 1]) * rskv * kvw[t * 8 + 2 * j + 1]);
    *(uint4*)(kv_n + (size_t)row * KVL + t * 8) = *(uint4*)o4;
  }
  if (t < 32) {
    const u16* src = xr + (QL + KVL) + 2 * t;
    float x0 = bf2f(src[0]), x1 = bf2f(src[1]);
    float ang = (float)pos[row] * __expf(-(float)t * LN1E4_32);
    float sn, cs; sincosf(ang, &sn, &cs);
    *(u32*)(peR + (size_t)row * 64 + 2 * t) = pack2(x0 * cs - x1 * sn, x1 * cs + x0 * sn);
  }
}

// ---------------- causal flash attention (reverted to R7: 16x16, VALU-dieted) ----------------
// 1024 blocks x 4 waves. Interior tiles (kb+32 <= q0) skip masking entirely;
// raw-domain max + fma-folded scale into exp2; cvt_pk P-pack.
__global__ __launch_bounds__(256)
void k_attn(const u16* __restrict__ Qf, const u16* __restrict__ KN,
            const u16* __restrict__ peR, const u16* __restrict__ VT,
            const int* __restrict__ pos, u16* __restrict__ Oa) {
  const int id = blockIdx.x;
  const int xk = id & 7, j = id >> 3;
  const int c = 31 - (j >> 2);
  const int bh = (j & 3) * 8 + xk;
  const int b = bh >> 4, h = bh & 15;
  const int t = threadIdx.x, lane = t & 63, wave = t >> 6;
  const int lq = lane & 15, lg = lane >> 4;
  const int q0 = c * 64 + wave * 16;
  const size_t vb = (size_t)bh * VD * SS;

  __shared__ u16 Ks[2][32 * 192];
  __shared__ u16 Vs[2][128 * 32];
  __shared__ u16 Pl[4][512];
  char* pl = (char*)&Pl[wave][0];
  const int swq = ((lq ^ (lq >> 2)) & 3) << 4;

  auto stage = [&](int buf, int kb) {
#pragma unroll
    for (int i = 0; i < 3; ++i) {      // K: 768 16B chunks (nope from KN, pe from peR)
      int cc = t + 256 * i, row = cc / 24, sl = cc % 24;
      int sg = sl ^ (row & 7);
      const u16* src = (sg < 16)
          ? KN + (size_t)(b * SS + kb + row) * 2048 + h * 128 + sg * 8
          : peR + (size_t)(b * SS + kb + row) * 64 + (sg - 16) * 8;
      gload_lds16(src, &Ks[buf][0] + cc * 8);
    }
#pragma unroll
    for (int i = 0; i < 2; ++i) {      // V: 512 16B chunks
      int cc = t + 256 * i, row = cc >> 2, sl = cc & 3;
      gload_lds16(VT + vb + (size_t)row * SS + kb + (sl ^ ((row >> 1) & 3)) * 8,
                  &Vs[buf][0] + cc * 8);
    }
  };

  const int token = b * SS + q0 + lq;
  bf16x8 qf[6];
#pragma unroll
  for (int ch = 0; ch < 6; ++ch)
    qf[ch] = *(const bf16x8*)(Qf + (size_t)token * (NH * QHD) + h * QHD + ch * 32 + lg * 8);
  // in-reg RoPE on q_pe chunks (4,5)
  const float posv = (float)pos[token];
#pragma unroll
  for (int ch = 4; ch < 6; ++ch)
#pragma unroll
    for (int p = 0; p < 4; ++p) {
      const int jj = (ch - 4) * 16 + lg * 4 + p;
      const float ang = posv * __expf(-(float)jj * LN1E4_32);
      float sn, cs; sincosf(ang, &sn, &cs);
      const float x0 = bf2f((u16)qf[ch][2 * p]), x1 = bf2f((u16)qf[ch][2 * p + 1]);
      qf[ch][2 * p]     = (short)f2bf(x0 * cs - x1 * sn);
      qf[ch][2 * p + 1] = (short)f2bf(x1 * cs + x0 * sn);
    }

  float m = -1e30f, lsum = 0.f;     // m in RAW score units
  f32x4 o[8];
#pragma unroll
  for (int vc = 0; vc < 8; ++vc) o[vc] = (f32x4){0.f, 0.f, 0.f, 0.f};

  const int nt = 2 * (c + 1);

  stage(0, 0);
  asm volatile("s_waitcnt vmcnt(0)" ::: "memory");
  __builtin_amdgcn_s_barrier();

  for (int tt = 0; tt < nt; ++tt) {
    const int cur = tt & 1;
    if (tt + 1 < nt) stage(cur ^ 1, (tt + 1) * 32);
    const int kb = tt * 32;

    if (kb < q0 + 16) {            // wave-uniform skip of fully-masked tiles
      f32x4 slo = (f32x4){0.f, 0.f, 0.f, 0.f};
      f32x4 shi = (f32x4){0.f, 0.f, 0.f, 0.f};
      __builtin_amdgcn_s_setprio(1);
#pragma unroll
      for (int ch = 0; ch < 6; ++ch) {
        const int ps = (ch * 4 + lg) ^ (lq & 7);
        bf16x8 klo = *(const bf16x8*)(&Ks[cur][0] + (lq * 24 + ps) * 8);
        bf16x8 khi = *(const bf16x8*)(&Ks[cur][0] + ((16 + lq) * 24 + ps) * 8);
        slo = __builtin_amdgcn_mfma_f32_16x16x32_bf16(klo, qf[ch], slo, 0, 0, 0);
        shi = __builtin_amdgcn_mfma_f32_16x16x32_bf16(khi, qf[ch], shi, 0, 0, 0);
      }
      __builtin_amdgcn_s_setprio(0);

      float mx;
      if (kb + 32 <= q0) {         // interior tile: no lane masked
        mx = fmaxf(fmaxf(fmaxf(slo[0], slo[1]), fmaxf(slo[2], slo[3])),
                   fmaxf(fmaxf(shi[0], shi[1]), fmaxf(shi[2], shi[3])));
      } else {                     // diagonal tile: mask in raw domain
        const int qrow = q0 + lq;
#pragma unroll
        for (int r = 0; r < 4; ++r) {
          int klo = kb + lg * 4 + r;
          slo[r] = (klo <= qrow)        ? slo[r] : -3e38f;
          shi[r] = ((klo + 16) <= qrow) ? shi[r] : -3e38f;
        }
        mx = fmaxf(fmaxf(fmaxf(slo[0], slo[1]), fmaxf(slo[2], slo[3])),
                   fmaxf(fmaxf(shi[0], shi[1]), fmaxf(shi[2], shi[3])));
      }
      mx = fmaxf(mx, __shfl_xor(mx, 16));
      mx = fmaxf(mx, __shfl_xor(mx, 32));
      if (!__all(mx - m <= THR_RAW)) {
        float mnew = fmaxf(m, mx);
        float fac = fexp2((m - mnew) * SCALE2);
        lsum *= fac;
#pragma unroll
        for (int vc = 0; vc < 8; ++vc) {
          o[vc][0] *= fac; o[vc][1] *= fac; o[vc][2] *= fac; o[vc][3] *= fac;
        }
        m = mnew;
      }
      const float ms = m * SCALE2;
      float p0 = fexp2(fmaf(slo[0], SCALE2, -ms)), p1 = fexp2(fmaf(slo[1], SCALE2, -ms));
      float p2 = fexp2(fmaf(slo[2], SCALE2, -ms)), p3 = fexp2(fmaf(slo[3], SCALE2, -ms));
      float p4 = fexp2(fmaf(shi[0], SCALE2, -ms)), p5 = fexp2(fmaf(shi[1], SCALE2, -ms));
      float p6 = fexp2(fmaf(shi[2], SCALE2, -ms)), p7 = fexp2(fmaf(shi[3], SCALE2, -ms));
      float ps2 = ((p0 + p1) + (p2 + p3)) + ((p4 + p5) + (p6 + p7));
      ps2 += __shfl_xor(ps2, 16);
      ps2 += __shfl_xor(ps2, 32);
      lsum += ps2;

      *(u32*)(pl + lq * 64 + ((8 * lg)          ^ swq)) = cvtpk(p0, p1);
      *(u32*)(pl + lq * 64 + ((8 * lg + 4)      ^ swq)) = cvtpk(p2, p3);
      *(u32*)(pl + lq * 64 + ((32 + 8 * lg)     ^ swq)) = cvtpk(p4, p5);
      *(u32*)(pl + lq * 64 + ((32 + 8 * lg + 4) ^ swq)) = cvtpk(p6, p7);
      bf16x8 pf = *(const bf16x8*)(pl + lq * 64 + ((16 * lg) ^ swq));
      __builtin_amdgcn_s_setprio(1);
#pragma unroll
      for (int vc = 0; vc < 8; ++vc) {
        const int rv = vc * 16 + lq;
        const int psv = lg ^ ((rv >> 1) & 3);
        bf16x8 vf = *(const bf16x8*)(&Vs[cur][0] + rv * 32 + psv * 8);
        o[vc] = __builtin_amdgcn_mfma_f32_16x16x32_bf16(vf, pf, o[vc], 0, 0, 0);
      }
      __builtin_amdgcn_s_setprio(0);
    }

    asm volatile("s_waitcnt vmcnt(0)" ::: "memory");
    __builtin_amdgcn_s_barrier();
  }

  const float inv = 1.0f / lsum;
  u16* orow = Oa + (size_t)token * (NH * VD) + h * VD;
#pragma unroll
  for (int vc = 0; vc < 8; ++vc) {
    *(u32*)(orow + vc * 16 + lg * 4)     = cvtpk(o[vc][0] * inv, o[vc][1] * inv);
    *(u32*)(orow + vc * 16 + lg * 4 + 2) = cvtpk(o[vc][2] * inv, o[vc][3] * inv);
  }
}

// ---------------- host launch ----------------
extern "C" void kernel_launch(void* const* d_in, const int* in_sizes, int n_in,
                              void* d_out, int out_size, void* d_ws, size_t ws_size,
                              hipStream_t stream) {
  (void)in_sizes; (void)n_in; (void)out_size; (void)ws_size;
  const float* hidden  = (const float*)d_in[0];
  const int*   pos     = (const int*)d_in[2];
  const float* q_a_w   = (const float*)d_in[3];
  const float* q_a_ln  = (const float*)d_in[4];
  const float* q_b_w   = (const float*)d_in[5];
  const float* kv_a_w  = (const float*)d_in[6];
  const float* kv_a_ln = (const float*)d_in[7];
  const float* kv_b_w  = (const float*)d_in[8];
  const float* o_w     = (const float*)d_in[9];

  char* ws = (char*)d_ws;
  u16* hid_bf = (u16*)(ws + 0);          // dead after GEMM1; region reused as VT
  u16* VT     = (u16*)(ws + 0);
  u16* w_comb = (u16*)(ws + 16777216);
  u16* w_qb   = (u16*)(ws + 25690112);
  u16* w_kvb  = (u16*)(ws + 35127296);
  u16* w_o    = (u16*)(ws + 39321600);
  u16* ac     = (u16*)(ws + 47710208);   // dead after k_token; reused as attn_o
  u16* attn_o = (u16*)(ws + 47710208);
  u16* qa_n   = (u16*)(ws + 65536000);
  u16* kv_n   = (u16*)(ws + 78118912);
  u16* qfull  = (u16*)(ws + 82313216);
  u16* KN     = (u16*)(ws + 107479040);  // TOK x 2048 compact k_nope
  u16* peR    = (u16*)(ws + 141033472);  // TOK x 64 roped k_pe

  k_f2bf_all<<<23168, 256, 0, stream>>>(hidden, q_a_w, kv_a_w, q_b_w, kv_b_w, o_w,
                                        hid_bf, w_comb, w_comb + QL * HID, w_qb, w_kvb, w_o);
  k_gemm1<<<144, 512, 0, stream>>>(hid_bf, w_comb, ac);
  k_token<<<TOK, 256, 0, stream>>>(ac, q_a_ln, kv_a_ln, pos, qa_n, kv_n, peR);
  k_gemm_qbkvb<<<448, 512, 0, stream>>>(qa_n, w_qb, qfull, kv_n, w_kvb, KN, VT);
  k_attn<<<1024, 256, 0, stream>>>(qfull, KN, peR, VT, pos, attn_o);
  k_oproj<<<128, 512, 0, stream>>>(attn_o, w_o, (float*)d_out);
}

// Round 10
// 300.678 us; speedup vs baseline: 1.1558x; 1.0404x over previous
//
#include <hip/hip_runtime.h>
#include <hip/hip_bf16.h>
#include <stdint.h>
#include <type_traits>

#define DEVINL __device__ __forceinline__

typedef unsigned short u16;
typedef unsigned int   u32;
typedef short bf16x8 __attribute__((ext_vector_type(8)));
typedef float f32x4  __attribute__((ext_vector_type(4)));

// ---- problem constants ----
constexpr int BB   = 2,  SS  = 2048, HID = 2048, NH = 16;
constexpr int NOPE = 128, VD = 128, QHD = 192;
constexpr int QL   = 1536, KVL = 512;
constexpr int TOK  = BB * SS;            // 4096 tokens
constexpr int NCOMB = 2176;              // ac row stride
constexpr int NREAL = 2112;              // real combined output cols (1536+512+64)
constexpr float SCALE2    = 0.10412907368573824f;   // 192^-0.5 * log2(e)
constexpr float THR_RAW   = 105.0f;                 // ~11 / SCALE2 (defer-max, raw units)
constexpr float LN1E4_32  = 0.28782313662425575f;   // ln(10000)/32

DEVINL float bf2f(u16 u) { union { u32 u; float f; } v; v.u = (u32)u << 16; return v.f; }
DEVINL u16 f2bf(float f) {
  union { float f; u32 u; } v; v.f = f;
  u32 r = v.u + 0x7fffu + ((v.u >> 16) & 1u);
  return (u16)(r >> 16);
}
DEVINL u32 pack2(float a, float b) { return (u32)f2bf(a) | ((u32)f2bf(b) << 16); }
DEVINL u32 cvtpk(float lo, float hi) {
  u32 r;
  asm("v_cvt_pk_bf16_f32 %0, %1, %2" : "=v"(r) : "v"(lo), "v"(hi));
  return r;
}

DEVINL float fexp2(float x) {
#if __has_builtin(__builtin_amdgcn_exp2f)
  return __builtin_amdgcn_exp2f(x);
#else
  return __expf(x * 0.6931471805599453f);
#endif
}

DEVINL void gload_lds16(const u16* g, u16* l) {
  __builtin_amdgcn_global_load_lds(
      (const __attribute__((address_space(1))) void*)g,
      (__attribute__((address_space(3))) void*)l, 16, 0, 0);
}

// ---------------- merged fp32 -> bf16 conversion (6 segments, one launch) ----------------
__global__ __launch_bounds__(256)
void k_f2bf_all(const float* __restrict__ s0, const float* __restrict__ s1,
                const float* __restrict__ s2, const float* __restrict__ s3,
                const float* __restrict__ s4, const float* __restrict__ s5,
                u16* __restrict__ d0, u16* __restrict__ d1, u16* __restrict__ d2,
                u16* __restrict__ d3, u16* __restrict__ d4, u16* __restrict__ d5) {
  long g = ((long)blockIdx.x * 256 + threadIdx.x) * 4;
  const float* s; u16* d; long off;
  if (g < 8388608L)       { s = s0; d = d0; off = g; }
  else if (g < 11534336L) { s = s1; d = d1; off = g - 8388608L; }
  else if (g < 12713984L) { s = s2; d = d2; off = g - 11534336L; }
  else if (g < 17432576L) { s = s3; d = d3; off = g - 12713984L; }
  else if (g < 19529728L) { s = s4; d = d4; off = g - 17432576L; }
  else                    { s = s5; d = d5; off = g - 19529728L; }
  float4 v = *(const float4*)(s + off);
  uint2 o; o.x = pack2(v.x, v.y); o.y = pack2(v.z, v.w);
  *(uint2*)(d + off) = o;
}

// ---------------- 128x128 2-phase counted-vmcnt NT GEMM body ----------------
// 4 waves (2M x 2N), per-wave 64x64 C, BK=64, 2-dbuf 64KB LDS -> 2 blocks/CU.
// Staging calendar: P0 stages B(T+1), P1 stages A(T+2); boundary vmcnt(4)
// retires exactly {A(T+1), B(T+1)}. Two barriers per K-tile:
//  B1 (post-P0-MFMA) protects P1's stageA(d,T+2) vs all waves' P0 a-reads;
//  B2 (post-vmcnt) makes next-tile staging completion collective.
template <class EPI>
DEVINL void gemm128_body(const u16* __restrict__ A, const u16* __restrict__ Bw,
                         int K, int m0, int n0, u16* SA, u16* SB, EPI epi) {
  const int t = threadIdx.x;           // 256 threads
  const int lane = t & 63, wave = t >> 6;
  const int wr = wave >> 1, wc = wave & 1;
  const int lq = lane & 15, lg = lane >> 4;
  const int NT = K >> 6;

  auto stage = [&](const u16* g, u16* l) {
#pragma unroll
    for (int i = 0; i < 4; ++i) {      // 1024 16B chunks, 4/thread
      int c = i * 256 + t, row = c >> 3;
      gload_lds16(g + (size_t)row * K + ((c & 7) ^ (row & 7)) * 8, l + c * 8);
    }
  };
  auto stageA = [&](int d, int kt) { stage(A + (size_t)m0 * K + kt * 64, SA + d * 8192); };
  auto stageB = [&](int d, int kt) { stage(Bw + (size_t)n0 * K + kt * 64, SB + d * 8192); };
  auto rdA = [&](int d, int m, int k) -> bf16x8 {
    int row = wr * 64 + m * 16 + lq;
    return *(const bf16x8*)(SA + d * 8192 + row * 64 + (((k * 4 + lg) ^ (row & 7)) * 8));
  };
  auto rdB = [&](int d, int n, int k) -> bf16x8 {
    int row = wc * 64 + n * 16 + lq;
    return *(const bf16x8*)(SB + d * 8192 + row * 64 + (((k * 4 + lg) ^ (row & 7)) * 8));
  };

  f32x4 acc[4][4] = {};
  bf16x8 a[4][2], b[4][2];

  stageA(0, 0); stageB(0, 0);
  if (NT > 1) stageA(1, 1);
  asm volatile("s_waitcnt vmcnt(4)" ::: "memory");
  __builtin_amdgcn_s_barrier();

  for (int T = 0; T < NT; ++T) {
    const int d = T & 1;
    // ---- P0: read a[0..3][*], b[0..1][*]; stage B(T+1); MFMA m x n0-1
#pragma unroll
    for (int m = 0; m < 4; ++m) { a[m][0] = rdA(d, m, 0); a[m][1] = rdA(d, m, 1); }
#pragma unroll
    for (int n = 0; n < 2; ++n) { b[n][0] = rdB(d, n, 0); b[n][1] = rdB(d, n, 1); }
    if (T + 1 < NT) stageB(d ^ 1, T + 1);
    asm volatile("s_waitcnt lgkmcnt(0)" ::: "memory");
#pragma unroll
    for (int m = 0; m < 4; ++m)
#pragma unroll
      for (int n = 0; n < 2; ++n) {
        acc[m][n] = __builtin_amdgcn_mfma_f32_16x16x32_bf16(a[m][0], b[n][0], acc[m][n], 0, 0, 0);
        acc[m][n] = __builtin_amdgcn_mfma_f32_16x16x32_bf16(a[m][1], b[n][1], acc[m][n], 0, 0, 0);
      }
    __builtin_amdgcn_s_barrier();      // B1: all waves' P0 LDS reads landed
    // ---- P1: read b[2..3][*]; stage A(T+2); MFMA m x n2-3
#pragma unroll
    for (int n = 2; n < 4; ++n) { b[n][0] = rdB(d, n, 0); b[n][1] = rdB(d, n, 1); }
    if (T + 2 < NT) stageA(d, T + 2);
    asm volatile("s_waitcnt lgkmcnt(0)" ::: "memory");
#pragma unroll
    for (int m = 0; m < 4; ++m)
#pragma unroll
      for (int n = 2; n < 4; ++n) {
        acc[m][n] = __builtin_amdgcn_mfma_f32_16x16x32_bf16(a[m][0], b[n][0], acc[m][n], 0, 0, 0);
        acc[m][n] = __builtin_amdgcn_mfma_f32_16x16x32_bf16(a[m][1], b[n][1], acc[m][n], 0, 0, 0);
      }
    if (T + 2 < NT)      asm volatile("s_waitcnt vmcnt(4)" ::: "memory");
    else if (T + 1 < NT) asm volatile("s_waitcnt vmcnt(0)" ::: "memory");
    __builtin_amdgcn_s_barrier();      // B2: next-tile staging collective
  }

#pragma unroll
  for (int m = 0; m < 4; ++m)
#pragma unroll
    for (int n = 0; n < 4; ++n)
      epi(m0 + wr * 64 + m * 16 + lg * 4, n0 + wc * 64 + n * 16 + lq, acc[m][n]);
}

// GEMM1: hidden @ w_comb^T -> ac. 544 blocks; XCD-chunked decode (m-fastest).
__global__ __launch_bounds__(256, 2)
void k_gemm1(const u16* __restrict__ A, const u16* __restrict__ Bw, u16* __restrict__ C) {
  __shared__ u16 SA[2 * 8192];
  __shared__ u16 SB[2 * 8192];
  const int L = (blockIdx.x & 7) * 68 + (blockIdx.x >> 3);
  const int n0 = (L >> 5) * 128, m0 = (L & 31) * 128;
  auto epi = [&](int row, int col, const f32x4& v) {
    if (col < NREAL) {
#pragma unroll
      for (int r = 0; r < 4; ++r) C[(size_t)(row + r) * NCOMB + col] = f2bf(v[r]);
    }
  };
  gemm128_body(A, Bw, HID, m0, n0, SA, SB, epi);
}

// grouped qb (768 blocks) + kvb (1024 blocks, epilogue splits KN / VT-transposed)
__global__ __launch_bounds__(256, 2)
void k_gemm_qbkvb(const u16* __restrict__ qa_n, const u16* __restrict__ w_qb,
                  u16* __restrict__ qfull, const u16* __restrict__ kv_n,
                  const u16* __restrict__ w_kvb, u16* __restrict__ KN,
                  u16* __restrict__ VT) {
  __shared__ u16 SA[2 * 8192];
  __shared__ u16 SB[2 * 8192];
  const int bx = blockIdx.x;
  if (bx < 768) {
    const int L = (bx & 7) * 96 + (bx >> 3);
    const int n0 = (L >> 5) * 128, m0 = (L & 31) * 128;
    auto epi = [&](int row, int col, const f32x4& v) {
#pragma unroll
      for (int r = 0; r < 4; ++r) qfull[(size_t)(row + r) * 3072 + col] = f2bf(v[r]);
    };
    gemm128_body(qa_n, w_qb, QL, m0, n0, SA, SB, epi);
  } else {
    const int i = bx - 768;
    const int L = (i & 7) * 128 + (i >> 3);
    const int n0 = (L >> 5) * 128, m0 = (L & 31) * 128;
    auto epi = [&](int row, int col, const f32x4& v) {
      const int h = col >> 8, d = col & 255;
      if (d < 128) {
#pragma unroll
        for (int r = 0; r < 4; ++r) KN[(size_t)(row + r) * 2048 + h * 128 + d] = f2bf(v[r]);
      } else {
        uint2 o; o.x = pack2(v[0], v[1]); o.y = pack2(v[2], v[3]);
        *(uint2*)(VT + ((size_t)((row >> 11) * 16 + h) * 128 + (d - 128)) * SS + (row & (SS - 1))) = o;
      }
    };
    gemm128_body(kv_n, w_kvb, KVL, m0, n0, SA, SB, epi);
  }
}

// o_proj -> fp32 d_out. 512 blocks = exactly 2/CU.
__global__ __launch_bounds__(256, 2)
void k_oproj(const u16* __restrict__ A, const u16* __restrict__ Bw, float* __restrict__ C) {
  __shared__ u16 SA[2 * 8192];
  __shared__ u16 SB[2 * 8192];
  const int L = (blockIdx.x & 7) * 64 + (blockIdx.x >> 3);
  const int n0 = (L >> 5) * 128, m0 = (L & 31) * 128;
  auto epi = [&](int row, int col, const f32x4& v) {
#pragma unroll
    for (int r = 0; r < 4; ++r) C[(size_t)(row + r) * HID + col] = v[r];
  };
  gemm128_body(A, Bw, NH * VD, m0, n0, SA, SB, epi);
}

// ---------------- fused per-token: RMSNorm(q), RMSNorm(kv), rope(k_pe) ----------------
__global__ __launch_bounds__(256)
void k_token(const u16* __restrict__ ac, const float* __restrict__ qw,
             const float* __restrict__ kvw, const int* __restrict__ pos,
             u16* __restrict__ qa_n, u16* __restrict__ kv_n, u16* __restrict__ peR) {
  const int row = blockIdx.x, t = threadIdx.x;
  const u16* xr = ac + (size_t)row * NCOMB;
  float sq = 0.f, skv = 0.f;
  if (t < 192) {
    bf16x8 v = *(const bf16x8*)(xr + t * 8);
#pragma unroll
    for (int j = 0; j < 8; ++j) { float f = bf2f((u16)v[j]); sq += f * f; }
  }
  if (t < 64) {
    bf16x8 v = *(const bf16x8*)(xr + QL + t * 8);
#pragma unroll
    for (int j = 0; j < 8; ++j) { float f = bf2f((u16)v[j]); skv += f * f; }
  }
#pragma unroll
  for (int o = 1; o < 64; o <<= 1) { sq += __shfl_xor(sq, o); skv += __shfl_xor(skv, o); }
  __shared__ float red[4][2];
  if ((t & 63) == 0) { red[t >> 6][0] = sq; red[t >> 6][1] = skv; }
  __syncthreads();
  const float rsq  = rsqrtf((red[0][0] + red[1][0] + red[2][0] + red[3][0]) / (float)QL  + 1e-6f);
  const float rskv = rsqrtf((red[0][1] + red[1][1] + red[2][1] + red[3][1]) / (float)KVL + 1e-6f);
  if (t < 192) {
    bf16x8 v = *(const bf16x8*)(xr + t * 8);
    u32 o4[4];
#pragma unroll
    for (int j = 0; j < 4; ++j)
      o4[j] = pack2(bf2f((u16)v[2 * j]) * rsq * qw[t * 8 + 2 * j],
                    bf2f((u16)v[2 * j + 1]) * rsq * qw[t * 8 + 2 * j + 1]);
    *(uint4*)(qa_n + (size_t)row * QL + t * 8) = *(uint4*)o4;
  }
  if (t < 64) {
    bf16x8 v = *(const bf16x8*)(xr + QL + t * 8);
    u32 o4[4];
#pragma unroll
    for (int j = 0; j < 4; ++j)
      o4[j] = pack2(bf2f((u16)v[2 * j]) * rskv * kvw[t * 8 + 2 * j],
                    bf2f((u16)v[2 * j + 1]) * rskv * kvw[t * 8 + 2 * j + 1]);
    *(uint4*)(kv_n + (size_t)row * KVL + t * 8) = *(uint4*)o4;
  }
  if (t < 32) {
    const u16* src = xr + (QL + KVL) + 2 * t;
    float x0 = bf2f(src[0]), x1 = bf2f(src[1]);
    float ang = (float)pos[row] * __expf(-(float)t * LN1E4_32);
    float sn, cs; sincosf(ang, &sn, &cs);
    *(u32*)(peR + (size_t)row * 64 + 2 * t) = pack2(x0 * cs - x1 * sn, x1 * cs + x0 * sn);
  }
}

// ---------------- causal flash attention (R7 structure, unchanged) ----------------
__global__ __launch_bounds__(256)
void k_attn(const u16* __restrict__ Qf, const u16* __restrict__ KN,
            const u16* __restrict__ peR, const u16* __restrict__ VT,
            const int* __restrict__ pos, u16* __restrict__ Oa) {
  const int id = blockIdx.x;
  const int xk = id & 7, j = id >> 3;
  const int c = 31 - (j >> 2);
  const int bh = (j & 3) * 8 + xk;
  const int b = bh >> 4, h = bh & 15;
  const int t = threadIdx.x, lane = t & 63, wave = t >> 6;
  const int lq = lane & 15, lg = lane >> 4;
  const int q0 = c * 64 + wave * 16;
  const size_t vb = (size_t)bh * VD * SS;

  __shared__ u16 Ks[2][32 * 192];
  __shared__ u16 Vs[2][128 * 32];
  __shared__ u16 Pl[4][512];
  char* pl = (char*)&Pl[wave][0];
  const int swq = ((lq ^ (lq >> 2)) & 3) << 4;

  auto stage = [&](int buf, int kb) {
#pragma unroll
    for (int i = 0; i < 3; ++i) {      // K: 768 16B chunks (nope from KN, pe from peR)
      int cc = t + 256 * i, row = cc / 24, sl = cc % 24;
      int sg = sl ^ (row & 7);
      const u16* src = (sg < 16)
          ? KN + (size_t)(b * SS + kb + row) * 2048 + h * 128 + sg * 8
          : peR + (size_t)(b * SS + kb + row) * 64 + (sg - 16) * 8;
      gload_lds16(src, &Ks[buf][0] + cc * 8);
    }
#pragma unroll
    for (int i = 0; i < 2; ++i) {      // V: 512 16B chunks
      int cc = t + 256 * i, row = cc >> 2, sl = cc & 3;
      gload_lds16(VT + vb + (size_t)row * SS + kb + (sl ^ ((row >> 1) & 3)) * 8,
                  &Vs[buf][0] + cc * 8);
    }
  };

  const int token = b * SS + q0 + lq;
  bf16x8 qf[6];
#pragma unroll
  for (int ch = 0; ch < 6; ++ch)
    qf[ch] = *(const bf16x8*)(Qf + (size_t)token * (NH * QHD) + h * QHD + ch * 32 + lg * 8);
  const float posv = (float)pos[token];
#pragma unroll
  for (int ch = 4; ch < 6; ++ch)
#pragma unroll
    for (int p = 0; p < 4; ++p) {
      const int jj = (ch - 4) * 16 + lg * 4 + p;
      const float ang = posv * __expf(-(float)jj * LN1E4_32);
      float sn, cs; sincosf(ang, &sn, &cs);
      const float x0 = bf2f((u16)qf[ch][2 * p]), x1 = bf2f((u16)qf[ch][2 * p + 1]);
      qf[ch][2 * p]     = (short)f2bf(x0 * cs - x1 * sn);
      qf[ch][2 * p + 1] = (short)f2bf(x1 * cs + x0 * sn);
    }

  float m = -1e30f, lsum = 0.f;     // m in RAW score units
  f32x4 o[8];
#pragma unroll
  for (int vc = 0; vc < 8; ++vc) o[vc] = (f32x4){0.f, 0.f, 0.f, 0.f};

  const int nt = 2 * (c + 1);

  stage(0, 0);
  asm volatile("s_waitcnt vmcnt(0)" ::: "memory");
  __builtin_amdgcn_s_barrier();

  for (int tt = 0; tt < nt; ++tt) {
    const int cur = tt & 1;
    if (tt + 1 < nt) stage(cur ^ 1, (tt + 1) * 32);
    const int kb = tt * 32;

    if (kb < q0 + 16) {
      f32x4 slo = (f32x4){0.f, 0.f, 0.f, 0.f};
      f32x4 shi = (f32x4){0.f, 0.f, 0.f, 0.f};
      __builtin_amdgcn_s_setprio(1);
#pragma unroll
      for (int ch = 0; ch < 6; ++ch) {
        const int ps = (ch * 4 + lg) ^ (lq & 7);
        bf16x8 klo = *(const bf16x8*)(&Ks[cur][0] + (lq * 24 + ps) * 8);
        bf16x8 khi = *(const bf16x8*)(&Ks[cur][0] + ((16 + lq) * 24 + ps) * 8);
        slo = __builtin_amdgcn_mfma_f32_16x16x32_bf16(klo, qf[ch], slo, 0, 0, 0);
        shi = __builtin_amdgcn_mfma_f32_16x16x32_bf16(khi, qf[ch], shi, 0, 0, 0);
      }
      __builtin_amdgcn_s_setprio(0);

      float mx;
      if (kb + 32 <= q0) {
        mx = fmaxf(fmaxf(fmaxf(slo[0], slo[1]), fmaxf(slo[2], slo[3])),
                   fmaxf(fmaxf(shi[0], shi[1]), fmaxf(shi[2], shi[3])));
      } else {
        const int qrow = q0 + lq;
#pragma unroll
        for (int r = 0; r < 4; ++r) {
          int klo = kb + lg * 4 + r;
          slo[r] = (klo <= qrow)        ? slo[r] : -3e38f;
          shi[r] = ((klo + 16) <= qrow) ? shi[r] : -3e38f;
        }
        mx = fmaxf(fmaxf(fmaxf(slo[0], slo[1]), fmaxf(slo[2], slo[3])),
                   fmaxf(fmaxf(shi[0], shi[1]), fmaxf(shi[2], shi[3])));
      }
      mx = fmaxf(mx, __shfl_xor(mx, 16));
      mx = fmaxf(mx, __shfl_xor(mx, 32));
      if (!__all(mx - m <= THR_RAW)) {
        float mnew = fmaxf(m, mx);
        float fac = fexp2((m - mnew) * SCALE2);
        lsum *= fac;
#pragma unroll
        for (int vc = 0; vc < 8; ++vc) {
          o[vc][0] *= fac; o[vc][1] *= fac; o[vc][2] *= fac; o[vc][3] *= fac;
        }
        m = mnew;
      }
      const float ms = m * SCALE2;
      float p0 = fexp2(fmaf(slo[0], SCALE2, -ms)), p1 = fexp2(fmaf(slo[1], SCALE2, -ms));
      float p2 = fexp2(fmaf(slo[2], SCALE2, -ms)), p3 = fexp2(fmaf(slo[3], SCALE2, -ms));
      float p4 = fexp2(fmaf(shi[0], SCALE2, -ms)), p5 = fexp2(fmaf(shi[1], SCALE2, -ms));
      float p6 = fexp2(fmaf(shi[2], SCALE2, -ms)), p7 = fexp2(fmaf(shi[3], SCALE2, -ms));
      float ps2 = ((p0 + p1) + (p2 + p3)) + ((p4 + p5) + (p6 + p7));
      ps2 += __shfl_xor(ps2, 16);
      ps2 += __shfl_xor(ps2, 32);
      lsum += ps2;

      *(u32*)(pl + lq * 64 + ((8 * lg)          ^ swq)) = cvtpk(p0, p1);
      *(u32*)(pl + lq * 64 + ((8 * lg + 4)      ^ swq)) = cvtpk(p2, p3);
      *(u32*)(pl + lq * 64 + ((32 + 8 * lg)     ^ swq)) = cvtpk(p4, p5);
      *(u32*)(pl + lq * 64 + ((32 + 8 * lg + 4) ^ swq)) = cvtpk(p6, p7);
      bf16x8 pf = *(const bf16x8*)(pl + lq * 64 + ((16 * lg) ^ swq));
      __builtin_amdgcn_s_setprio(1);
#pragma unroll
      for (int vc = 0; vc < 8; ++vc) {
        const int rv = vc * 16 + lq;
        const int psv = lg ^ ((rv >> 1) & 3);
        bf16x8 vf = *(const bf16x8*)(&Vs[cur][0] + rv * 32 + psv * 8);
        o[vc] = __builtin_amdgcn_mfma_f32_16x16x32_bf16(vf, pf, o[vc], 0, 0, 0);
      }
      __builtin_amdgcn_s_setprio(0);
    }

    asm volatile("s_waitcnt vmcnt(0)" ::: "memory");
    __builtin_amdgcn_s_barrier();
  }

  const float inv = 1.0f / lsum;
  u16* orow = Oa + (size_t)token * (NH * VD) + h * VD;
#pragma unroll
  for (int vc = 0; vc < 8; ++vc) {
    *(u32*)(orow + vc * 16 + lg * 4)     = cvtpk(o[vc][0] * inv, o[vc][1] * inv);
    *(u32*)(orow + vc * 16 + lg * 4 + 2) = cvtpk(o[vc][2] * inv, o[vc][3] * inv);
  }
}

// ---------------- host launch ----------------
extern "C" void kernel_launch(void* const* d_in, const int* in_sizes, int n_in,
                              void* d_out, int out_size, void* d_ws, size_t ws_size,
                              hipStream_t stream) {
  (void)in_sizes; (void)n_in; (void)out_size; (void)ws_size;
  const float* hidden  = (const float*)d_in[0];
  const int*   pos     = (const int*)d_in[2];
  const float* q_a_w   = (const float*)d_in[3];
  const float* q_a_ln  = (const float*)d_in[4];
  const float* q_b_w   = (const float*)d_in[5];
  const float* kv_a_w  = (const float*)d_in[6];
  const float* kv_a_ln = (const float*)d_in[7];
  const float* kv_b_w  = (const float*)d_in[8];
  const float* o_w     = (const float*)d_in[9];

  char* ws = (char*)d_ws;
  u16* hid_bf = (u16*)(ws + 0);          // dead after GEMM1; region reused as VT
  u16* VT     = (u16*)(ws + 0);
  u16* w_comb = (u16*)(ws + 16777216);
  u16* w_qb   = (u16*)(ws + 25690112);
  u16* w_kvb  = (u16*)(ws + 35127296);
  u16* w_o    = (u16*)(ws + 39321600);
  u16* ac     = (u16*)(ws + 47710208);   // dead after k_token; reused as attn_o
  u16* attn_o = (u16*)(ws + 47710208);
  u16* qa_n   = (u16*)(ws + 65536000);
  u16* kv_n   = (u16*)(ws + 78118912);
  u16* qfull  = (u16*)(ws + 82313216);
  u16* KN     = (u16*)(ws + 107479040);  // TOK x 2048 compact k_nope
  u16* peR    = (u16*)(ws + 141033472);  // TOK x 64 roped k_pe

  k_f2bf_all<<<23168, 256, 0, stream>>>(hidden, q_a_w, kv_a_w, q_b_w, kv_b_w, o_w,
                                        hid_bf, w_comb, w_comb + QL * HID, w_qb, w_kvb, w_o);
  k_gemm1<<<544, 256, 0, stream>>>(hid_bf, w_comb, ac);
  k_token<<<TOK, 256, 0, stream>>>(ac, q_a_ln, kv_a_ln, pos, qa_n, kv_n, peR);
  k_gemm_qbkvb<<<1792, 256, 0, stream>>>(qa_n, w_qb, qfull, kv_n, w_kvb, KN, VT);
  k_attn<<<1024, 256, 0, stream>>>(qfull, KN, peR, VT, pos, attn_o);
  k_oproj<<<512, 256, 0, stream>>>(attn_o, w_o, (float*)d_out);
}